// Round 10
// baseline (251.646 us; speedup 1.0000x reference)
//
#include <hip/hip_runtime.h>
#include <math.h>

#define HD 128
#define WD 128
#define BB 32
#define KK 32
#define NPIX (BB*HD*WD)   // 524288
#define PLANE ((size_t)NPIX*8)   // f16 elems per plane

typedef _Float16 f16;
typedef __attribute__((ext_vector_type(8))) _Float16 f16x8;
typedef __attribute__((ext_vector_type(4))) _Float16 f16x4;
typedef __attribute__((ext_vector_type(4))) float f32x4;

// byte offset of 16B chunk g within 64B row; bijective over (row mod 8) -> all 32 banks
__device__ __forceinline__ int swz(int row, int g){
  return row*64 + (((g + (row >> 1)) & 3) << 4);
}

__device__ __forceinline__ float xexp2(float x){
#if __has_builtin(__builtin_amdgcn_exp2f)
  return __builtin_amdgcn_exp2f(x);
#else
  return exp2f(x);
#endif
}
__device__ __forceinline__ float xrcp(float x){
#if __has_builtin(__builtin_amdgcn_rcpf)
  return __builtin_amdgcn_rcpf(x);
#else
  return 1.f/x;
#endif
}
__device__ __forceinline__ f16x8 bc8(f16 x){
  f16x8 v;
  #pragma unroll
  for (int j = 0; j < 8; j++) v[j] = x;
  return v;
}

#define WSCALE 2.8853900817779268f   // 2*log2(e)

// ---------------- fused CNN + affinity (unchanged from R9) ----------------
__global__ __launch_bounds__(512, 4) void cnnaff_kernel(
    const int* __restrict__ X,
    const float* __restrict__ w1, const float* __restrict__ b1,
    const float* __restrict__ w2, const float* __restrict__ b2,
    const float* __restrict__ w3, const float* __restrict__ b3,
    float* __restrict__ wb)
{
  __shared__ f16 sW1f[9*11*40];
  __shared__ int   sX[22*38];
  __shared__ float sB2[32], sB3[32];
  __shared__ f16 x1[720*32];
  __shared__ f16 w2t[9*32*32];
  __shared__ f16 w3t[32*32];

  const int tid = threadIdx.x;
  const int img = blockIdx.z;
  const int bh0 = blockIdx.y * 16;
  const int bw0 = blockIdx.x * 32;

  for (int i = tid; i < 9*11*32; i += 512) {
    int tap = i / 352, c = (i % 352) >> 5, oc = i & 31;
    float v = (c < 10) ? w1[tap*320 + c*32 + oc] : 0.f;
    if (tap == 4 && c < 10) v += b1[oc];
    sW1f[(tap*11 + c)*40 + oc] = (f16)v;
  }
  for (int i = tid; i < 9*32*32; i += 512) {
    int tap = i >> 10, ic = (i >> 5) & 31, oc = i & 31;
    int off = swz(tap*32 + oc, ic >> 3) + (ic & 7)*2;
    *(f16*)((char*)w2t + off) = (f16)w2[i];
  }
  for (int i = tid; i < 32*32; i += 512) {
    int ic = i >> 5, oe = i & 31;
    int off = swz(oe, ic >> 3) + (ic & 7)*2;
    *(f16*)((char*)w3t + off) = (f16)w3[i];
  }
  if (tid < 32) { sB2[tid] = b2[tid]; sB3[tid] = b3[tid]; }
  for (int i = tid; i < 22*38; i += 512) {
    int ti = i / 38, tj = i % 38;
    int gh = bh0 - 3 + ti, gw = bw0 - 3 + tj;
    sX[i] = (gh >= 0 && gh < HD && gw >= 0 && gw < WD) ? X[(img*HD + gh)*WD + gw] : 10;
  }
  __syncthreads();

  for (int p = tid; p < 720; p += 512) {
    int r = p / 36, c = p - r*36;
    int gh = bh0 - 2 + r, gw = bw0 - 2 + c;
    if (gh >= 0 && gh < HD && gw >= 0 && gw < WD) {
      f16x8 acc[4];
      {
        int cc = sX[r*38 + c];
        const f16* wr = &sW1f[cc*40];
        #pragma unroll
        for (int g = 0; g < 4; g++) acc[g] = *(const f16x8*)(wr + g*8);
      }
      #pragma unroll
      for (int tap = 1; tap < 9; tap++) {
        const int ti = tap/3, tj = tap%3;
        int cc = sX[(r+ti)*38 + c + tj];
        const f16* wr = &sW1f[(tap*11 + cc)*40];
        #pragma unroll
        for (int g = 0; g < 4; g++) acc[g] += *(const f16x8*)(wr + g*8);
      }
      #pragma unroll
      for (int g = 0; g < 4; g++) {
        f16x8 rr = acc[g];
        #pragma unroll
        for (int j = 0; j < 8; j++) rr[j] = (rr[j] > (f16)0.f) ? rr[j] : (f16)0.f;
        *(f16x8*)((char*)x1 + swz(p, g)) = rr;
      }
    } else {
      f16x8 z;
      #pragma unroll
      for (int j = 0; j < 8; j++) z[j] = (f16)0.f;
      #pragma unroll
      for (int g = 0; g < 4; g++) *(f16x8*)((char*)x1 + swz(p, g)) = z;
    }
  }
  __syncthreads();

  const int lane = tid & 63;
  const int wv   = tid >> 6;
  const int lr   = lane & 15;
  const int kg   = lane >> 4;
  const int mts  = wv * 5;

  int arow0[5];
  #pragma unroll
  for (int q = 0; q < 5; q++) {
    int px = (mts + q)*16 + lr;
    int pr = px / 34, pc = px - pr*34;
    arow0[q] = pr*36 + pc;
  }
  float b2v0 = sB2[lr], b2v1 = sB2[lr + 16];
  f32x4 acc[5][2];
  #pragma unroll
  for (int q = 0; q < 5; q++) {
    acc[q][0] = (f32x4){b2v0, b2v0, b2v0, b2v0};
    acc[q][1] = (f32x4){b2v1, b2v1, b2v1, b2v1};
  }
  #pragma unroll
  for (int tap = 0; tap < 9; tap++) {
    const int ti = tap/3, tj = tap%3;
    f16x8 bf0 = *(const f16x8*)((const char*)w2t + swz(tap*32 + lr,      kg));
    f16x8 bf1 = *(const f16x8*)((const char*)w2t + swz(tap*32 + lr + 16, kg));
    #pragma unroll
    for (int q = 0; q < 5; q++) {
      int row = arow0[q] + ti*36 + tj;
      f16x8 af = *(const f16x8*)((const char*)x1 + swz(row, kg));
      acc[q][0] = __builtin_amdgcn_mfma_f32_16x16x32_f16(af, bf0, acc[q][0], 0, 0, 0);
      acc[q][1] = __builtin_amdgcn_mfma_f32_16x16x32_f16(af, bf1, acc[q][1], 0, 0, 0);
    }
  }
  __syncthreads();

  #pragma unroll
  for (int q = 0; q < 5; q++)
    #pragma unroll
    for (int nt = 0; nt < 2; nt++) {
      int oc = nt*16 + lr;
      #pragma unroll
      for (int rg = 0; rg < 4; rg++) {
        int px = (mts + q)*16 + kg*4 + rg;
        int off = swz(px, oc >> 3) + (oc & 7)*2;
        *(f16*)((char*)x1 + off) = (f16)fmaxf(acc[q][nt][rg], 0.f);
      }
    }
  __syncthreads();

  {
    f16x8 cf0 = *(const f16x8*)((const char*)w3t + swz(lr,      kg));
    f16x8 cf1 = *(const f16x8*)((const char*)w3t + swz(lr + 16, kg));
    float b3v0 = sB3[lr], b3v1 = sB3[lr + 16];
    #pragma unroll
    for (int q = 0; q < 5; q++) {
      f16x8 af = *(const f16x8*)((const char*)x1 + swz((mts + q)*16 + lr, kg));
      f32x4 o0 = (f32x4){b3v0, b3v0, b3v0, b3v0};
      f32x4 o1 = (f32x4){b3v1, b3v1, b3v1, b3v1};
      o0 = __builtin_amdgcn_mfma_f32_16x16x32_f16(af, cf0, o0, 0, 0, 0);
      o1 = __builtin_amdgcn_mfma_f32_16x16x32_f16(af, cf1, o1, 0, 0, 0);
      #pragma unroll
      for (int rg = 0; rg < 4; rg++) {
        int px = (mts + q)*16 + kg*4 + rg;
        int offA = swz(px, lr >> 3) + (lr & 7)*2;
        int offB = swz(px, (lr+16) >> 3) + (lr & 7)*2;
        *(f16*)((char*)x1 + offA) = (f16)o0[rg];
        *(f16*)((char*)x1 + offB) = (f16)o1[rg];
      }
    }
  }
  __syncthreads();

  {
    int r2 = tid >> 5, c2 = tid & 31;
    int gh = bh0 + r2, gw = bw0 + c2;
    int qc = (r2+1)*34 + (c2+1);
    f16x8 c0 = *(const f16x8*)((const char*)x1 + swz(qc, 0));
    f16x8 c1 = *(const f16x8*)((const char*)x1 + swz(qc, 1));
    f16x8 c2v = *(const f16x8*)((const char*)x1 + swz(qc, 2));
    f16x8 c3 = *(const f16x8*)((const char*)x1 + swz(qc, 3));
    float4 out;
    #pragma unroll
    for (int d = 0; d < 4; d++) {
      int slot = (d == 0) ? qc + 34 : (d == 1) ? qc - 34 : (d == 2) ? qc + 1 : qc - 1;
      bool valid = (d == 0) ? (gh < HD-1) : (d == 1) ? (gh > 0) : (d == 2) ? (gw < WD-1) : (gw > 0);
      f16x8 n0 = *(const f16x8*)((const char*)x1 + swz(slot, 0));
      f16x8 n1 = *(const f16x8*)((const char*)x1 + swz(slot, 1));
      f16x8 n2 = *(const f16x8*)((const char*)x1 + swz(slot, 2));
      f16x8 n3 = *(const f16x8*)((const char*)x1 + swz(slot, 3));
      f16x8 d0 = c0 - n0; f16x8 s = d0*d0;
      f16x8 d1 = c1 - n1; s += d1*d1;
      f16x8 d2 = c2v - n2; s += d2*d2;
      f16x8 d3 = c3 - n3; s += d3*d3;
      float d2f = 0.f;
      #pragma unroll
      for (int j = 0; j < 8; j++) d2f += (float)s[j];
      float v = valid ? WSCALE * xexp2(-WSCALE * d2f) : 0.f;
      if (d == 0) out.x = v; else if (d == 1) out.y = v; else if (d == 2) out.z = v; else out.w = v;
    }
    ((float4*)wb)[(size_t)img*HD*WD + gh*WD + gw] = out;
  }
}

// ---------------- separable analytic A0 helpers ----------------
__device__ __forceinline__ void a0_row(float fh, float* eh, float& s){
  const float C = 0.0028177637517362567f;  // log2(e)/512
  s = 0.f;
  #pragma unroll
  for (int kh = 0; kh < 4; kh++){ float d = fh - (float)(kh*32+16); eh[kh] = xexp2(-d*d*C); s += eh[kh]; }
}
__device__ __forceinline__ void a0_col(float fw, float* ew, float& s){
  const float C = 0.0028177637517362567f;
  s = 0.f;
  #pragma unroll
  for (int kw = 0; kw < 8; kw++){ float d = fw - (float)(kw*16+8); ew[kw] = xexp2(-d*d*C); s += ew[kw]; }
}

// ---------------- one regular message-pass px from LDS ----------------
__device__ __forceinline__ void mp_px_reg(const f16* __restrict__ amid, int slot,
                                          int du, int dd, int dl, int dr,
                                          float4 wd, f16x8* out) {
  f16x8 w0 = bc8((f16)wd.x), w1 = bc8((f16)wd.y), w2 = bc8((f16)wd.z), w3 = bc8((f16)wd.w);
  float s = 0.f;
  f16x8 pe[4];
  #pragma unroll
  for (int g = 0; g < 4; g++) {
    f16x8 v0 = *(const f16x8*)((const char*)amid + swz(slot + du, g));
    f16x8 v1 = *(const f16x8*)((const char*)amid + swz(slot + dd, g));
    f16x8 v2 = *(const f16x8*)((const char*)amid + swz(slot + dl, g));
    f16x8 v3 = *(const f16x8*)((const char*)amid + swz(slot + dr, g));
    f16x8 agg = v0*w0 + v1*w1 + v2*w2 + v3*w3;
    #pragma unroll
    for (int j = 0; j < 8; j++) { float e = xexp2((float)agg[j]); s += e; pe[g][j] = (f16)e; }
  }
  f16x8 iv = bc8((f16)xrcp(s));
  #pragma unroll
  for (int g = 0; g < 4; g++) out[g] = pe[g]*iv;
}

// ---------------- analytic iter-1 px (separable, 36+32 exps) ----------------
__device__ __forceinline__ void mp_px_a0(int gh, int gw, float4 wd, f16x8* out) {
  int ghc = min(max(gh, 0), HD-1), gwc = min(max(gw, 0), WD-1);
  int hu = ghc + ((ghc < HD-1) ? 1 : 0);
  int hd = ghc - ((ghc > 0)    ? 1 : 0);
  int wl = gwc + ((gwc < WD-1) ? 1 : 0);
  int wr = gwc - ((gwc > 0)    ? 1 : 0);
  float eh[4], ehu[4], ehd[4], ew[8], ewl[8], ewr[8];
  float Sh, Shu, Shd, Sw, Swl, Swr;
  a0_row((float)ghc, eh, Sh); a0_row((float)hu, ehu, Shu); a0_row((float)hd, ehd, Shd);
  a0_col((float)gwc, ew, Sw); a0_col((float)wl, ewl, Swl); a0_col((float)wr, ewr, Swr);
  float cu = wd.x * xrcp(Shu * Sw);
  float cd = wd.y * xrcp(Shd * Sw);
  float cl = wd.z * xrcp(Sh * Swl);
  float cr = wd.w * xrcp(Sh * Swr);
  float c1[4], c2[8];
  #pragma unroll
  for (int kh = 0; kh < 4; kh++) c1[kh] = cu*ehu[kh] + cd*ehd[kh];
  #pragma unroll
  for (int kw = 0; kw < 8; kw++) c2[kw] = cl*ewl[kw] + cr*ewr[kw];
  float s = 0.f;
  f16x8 pe[4];
  #pragma unroll
  for (int g = 0; g < 4; g++)
    #pragma unroll
    for (int j = 0; j < 8; j++) {
      float aa = fmaf(c1[g], ew[j], eh[g]*c2[j]);
      float e = xexp2(aa); s += e; pe[g][j] = (f16)e;
    }
  f16x8 iv = bc8((f16)xrcp(s));
  #pragma unroll
  for (int g = 0; g < 4; g++) out[g] = pe[g]*iv;
}

// ---------------- fused 4-iteration message pass ----------------
// tile 16x32 output, 24x40 LDS frame (origin -4,-4), in-place shrinking-region iterations
template<int FIRST, int LAST>
__global__ __launch_bounds__(512, 4) void mp4_kernel(const f16* __restrict__ Ain,
                                                     const float* __restrict__ wb,
                                                     f16* __restrict__ Aout,
                                                     float* __restrict__ AoutF) {
  __shared__ f16 amid[960*32];   // 60 KB: 24x40 frame, swizzled 64B rows

  const int blk  = blockIdx.x;          // 1024
  const int xcd  = blk & 7;
  const int q    = blk >> 3;
  const int img  = xcd + ((q >> 5) << 3);
  const int tile = q & 31;
  const int th0  = (tile >> 2) * 16;
  const int tw0  = (tile & 3) * 32;
  const size_t ibase = (size_t)img * HD * WD;

  if (!FIRST) {
    // stage A planes into 24x40 frame (replicate-edge clamp), coalesced per plane
    for (int t = threadIdx.x; t < 3840; t += 512) {
      int g = t / 960, slot = t - g*960;
      int sr = slot / 40, sc = slot - sr*40;
      int gh = min(max(th0 + sr - 4, 0), HD-1);
      int gw = min(max(tw0 + sc - 4, 0), WD-1);
      f16x8 v = *(const f16x8*)(Ain + (size_t)g*PLANE + (ibase + (size_t)gh*WD + gw)*8);
      *(f16x8*)((char*)amid + swz(slot, g)) = v;
    }
    __syncthreads();
  }

  // ---- iteration 1 on (22,38,-3) ----
  {
    constexpr int N = 22*38;   // 836
    f16x8 r0[4], r1[4];
    int slot0, slot1 = 0;
    const bool own1 = (threadIdx.x + 512) < N;
    {
      int p = threadIdx.x;
      int r = p / 38, c = p - r*38;
      int gh = th0 - 3 + r, gw = tw0 - 3 + c;
      slot0 = (r + 1)*40 + (c + 1);
      bool inimg = ((unsigned)gh < (unsigned)HD) && ((unsigned)gw < (unsigned)WD);
      float4 wd = inimg ? ((const float4*)wb)[ibase + gh*WD + gw] : make_float4(0.f,0.f,0.f,0.f);
      if (FIRST) mp_px_a0(gh, gw, wd, r0);
      else {
        int du = (gh < HD-1) ? 40 : 0, dd = (gh > 0) ? -40 : 0;
        int dl = (gw < WD-1) ? 1 : 0,  dr = (gw > 0) ? -1 : 0;
        mp_px_reg(amid, slot0, du, dd, dl, dr, wd, r0);
      }
    }
    if (own1) {
      int p = threadIdx.x + 512;
      int r = p / 38, c = p - r*38;
      int gh = th0 - 3 + r, gw = tw0 - 3 + c;
      slot1 = (r + 1)*40 + (c + 1);
      bool inimg = ((unsigned)gh < (unsigned)HD) && ((unsigned)gw < (unsigned)WD);
      float4 wd = inimg ? ((const float4*)wb)[ibase + gh*WD + gw] : make_float4(0.f,0.f,0.f,0.f);
      if (FIRST) mp_px_a0(gh, gw, wd, r1);
      else {
        int du = (gh < HD-1) ? 40 : 0, dd = (gh > 0) ? -40 : 0;
        int dl = (gw < WD-1) ? 1 : 0,  dr = (gw > 0) ? -1 : 0;
        mp_px_reg(amid, slot1, du, dd, dl, dr, wd, r1);
      }
    }
    __syncthreads();
    #pragma unroll
    for (int g = 0; g < 4; g++) *(f16x8*)((char*)amid + swz(slot0, g)) = r0[g];
    if (own1) {
      #pragma unroll
      for (int g = 0; g < 4; g++) *(f16x8*)((char*)amid + swz(slot1, g)) = r1[g];
    }
    __syncthreads();
  }

  // ---- iterations 2,3 on (20,36,-2) and (18,34,-1) ----
  #define MP_ITER(HH, WW, OO)                                                        \
  {                                                                                  \
    constexpr int N = (HH)*(WW);                                                     \
    f16x8 r0[4], r1[4];                                                              \
    int slot0, slot1 = 0;                                                            \
    const bool own1 = (threadIdx.x + 512) < N;                                       \
    {                                                                                \
      int p = threadIdx.x;                                                           \
      int r = p / (WW), c = p - r*(WW);                                              \
      int gh = th0 + (OO) + r, gw = tw0 + (OO) + c;                                  \
      slot0 = (r + (OO) + 4)*40 + (c + (OO) + 4);                                    \
      bool inimg = ((unsigned)gh < (unsigned)HD) && ((unsigned)gw < (unsigned)WD);   \
      float4 wd = inimg ? ((const float4*)wb)[ibase + gh*WD + gw]                    \
                        : make_float4(0.f,0.f,0.f,0.f);                              \
      int du = (gh < HD-1) ? 40 : 0, dd = (gh > 0) ? -40 : 0;                        \
      int dl = (gw < WD-1) ? 1 : 0,  dr = (gw > 0) ? -1 : 0;                         \
      mp_px_reg(amid, slot0, du, dd, dl, dr, wd, r0);                                \
    }                                                                                \
    if (own1) {                                                                      \
      int p = threadIdx.x + 512;                                                     \
      int r = p / (WW), c = p - r*(WW);                                              \
      int gh = th0 + (OO) + r, gw = tw0 + (OO) + c;                                  \
      slot1 = (r + (OO) + 4)*40 + (c + (OO) + 4);                                    \
      bool inimg = ((unsigned)gh < (unsigned)HD) && ((unsigned)gw < (unsigned)WD);   \
      float4 wd = inimg ? ((const float4*)wb)[ibase + gh*WD + gw]                    \
                        : make_float4(0.f,0.f,0.f,0.f);                              \
      int du = (gh < HD-1) ? 40 : 0, dd = (gh > 0) ? -40 : 0;                        \
      int dl = (gw < WD-1) ? 1 : 0,  dr = (gw > 0) ? -1 : 0;                         \
      mp_px_reg(amid, slot1, du, dd, dl, dr, wd, r1);                                \
    }                                                                                \
    __syncthreads();                                                                 \
    _Pragma("unroll")                                                                \
    for (int g = 0; g < 4; g++) *(f16x8*)((char*)amid + swz(slot0, g)) = r0[g];      \
    if (own1) {                                                                      \
      _Pragma("unroll")                                                              \
      for (int g = 0; g < 4; g++) *(f16x8*)((char*)amid + swz(slot1, g)) = r1[g];    \
    }                                                                                \
    __syncthreads();                                                                 \
  }

  MP_ITER(20, 36, -2)
  MP_ITER(18, 34, -1)
  #undef MP_ITER

  // ---- iteration 4 on (16,32,0): final, to global ----
  {
    int r = threadIdx.x >> 5, c = threadIdx.x & 31;
    int gh = th0 + r, gw = tw0 + c;
    int slot = (r + 4)*40 + (c + 4);
    float4 wd = ((const float4*)wb)[ibase + gh*WD + gw];
    int du = (gh < HD-1) ? 40 : 0, dd = (gh > 0) ? -40 : 0;
    int dl = (gw < WD-1) ? 1 : 0,  dr = (gw > 0) ? -1 : 0;
    f16x8 pe[4];
    mp_px_reg(amid, slot, du, dd, dl, dr, wd, pe);

    if (!LAST) {
      size_t opix = ibase + (size_t)gh*WD + gw;
      #pragma unroll
      for (int g = 0; g < 4; g++)
        *(f16x8*)(Aout + (size_t)g*PLANE + opix*8) = pe[g];
    } else {
      __syncthreads();                       // amid reads complete
      f16* planes = amid;
      #pragma unroll
      for (int g = 0; g < 4; g++)
        *(f16x8*)((char*)planes + (g*513 + threadIdx.x)*16) = pe[g];
      __syncthreads();
      float* obase = AoutF + ((size_t)(img*HD + th0)*WD + tw0)*32;
      #pragma unroll
      for (int rep = 0; rep < 8; rep++) {
        int flat = rep*512 + threadIdx.x;     // 0..4095 chunks of 16B
        int row = flat >> 8;
        int within = flat & 255;
        int pxr = within >> 3;
        int kq = within & 7;
        int g = kq >> 1, half = kq & 1;
        int pxl = row*32 + pxr;
        f16x4 v = *(const f16x4*)((const char*)planes + (g*513 + pxl)*16 + half*8);
        float4 o;
        o.x = (float)v[0]; o.y = (float)v[1]; o.z = (float)v[2]; o.w = (float)v[3];
        *(float4*)(obase + (size_t)row*WD*32 + pxr*32 + kq*4) = o;
      }
    }
  }
}

// ---------------- pooled features, stage 1 (reads canonical f32 A) ----------------
__global__ __launch_bounds__(256) void pool1_kernel(const float* __restrict__ A,
                                                    const int* __restrict__ X,
                                                    float* __restrict__ part) {
  const int b = blockIdx.x, cy = blockIdx.y;
  const int k = threadIdx.x & 31, sub = threadIdx.x >> 5;
  const int h = cy*4 + (sub >> 1);
  const int w0 = (sub & 1) * 64;
  const float hh = ((float)h + 0.5f) * (1.f/128.f);
  float s0 = 0.f, sw = 0.f, sw2 = 0.f;
  float col[10];
  #pragma unroll
  for (int c = 0; c < 10; c++) col[c] = 0.f;
  const float* Arow = A + ((size_t)((b*HD + h)*WD + w0))*32 + k;
  const int*   Xrow = X + (b*HD + h)*WD + w0;
  for (int w = 0; w < 64; w++) {
    float a  = Arow[(size_t)w*32];
    float ww = ((float)(w + w0) + 0.5f) * (1.f/128.f);
    s0 += a; sw = fmaf(ww, a, sw); sw2 = fmaf(ww*ww, a, sw2);
    int x = Xrow[w];
    #pragma unroll
    for (int c = 0; c < 10; c++) col[c] += (x == c) ? a : 0.f;
  }
  __shared__ float red[8][32][15];
  float vals[15];
  vals[0] = s0; vals[1] = hh*s0; vals[2] = sw; vals[3] = hh*hh*s0; vals[4] = sw2;
  #pragma unroll
  for (int c = 0; c < 10; c++) vals[5+c] = col[c];
  #pragma unroll
  for (int q = 0; q < 15; q++) red[sub][k][q] = vals[q];
  __syncthreads();
  if (sub == 0) {
    #pragma unroll
    for (int q = 0; q < 15; q++) {
      float v = 0.f;
      #pragma unroll
      for (int s2 = 0; s2 < 8; s2++) v += red[s2][k][q];
      part[(((size_t)b*32 + cy)*32 + k)*15 + q] = v;
    }
  }
}

// ---------------- pooled features, stage 2 ----------------
__global__ __launch_bounds__(256) void pool2_kernel(const float* __restrict__ part,
                                                    float* __restrict__ T) {
  const int t = blockIdx.x * 256 + threadIdx.x;
  if (t >= BB*KK) return;
  const int b = t >> 5, k = t & 31;
  float s[15];
  #pragma unroll
  for (int q = 0; q < 15; q++) s[q] = 0.f;
  for (int cy = 0; cy < 32; cy++) {
    const float* p = part + (((size_t)b*32 + cy)*32 + k)*15;
    #pragma unroll
    for (int q = 0; q < 15; q++) s[q] += p[q];
  }
  float mass = s[0] + 1e-6f;
  float inv  = 1.f / mass;
  float h_c = s[1]*inv, w_c = s[2]*inv, h2 = s[3]*inv, w2 = s[4]*inv;
  float h_sd = sqrtf(fmaxf(h2 - h_c*h_c, 0.f) + 1e-6f);
  float w_sd = sqrtf(fmaxf(w2 - w_c*w_c, 0.f) + 1e-6f);
  float* o = T + (size_t)t*17;
  o[0] = mass * (1.f/16384.f);
  o[1] = h_c; o[2] = w_c;
  #pragma unroll
  for (int c = 0; c < 10; c++) o[3+c] = s[5+c]*inv;
  o[13] = h_c - h_sd; o[14] = h_c + h_sd; o[15] = w_c - w_sd; o[16] = w_c + w_sd;
}

extern "C" void kernel_launch(void* const* d_in, const int* in_sizes, int n_in,
                              void* d_out, int out_size, void* d_ws, size_t ws_size,
                              hipStream_t stream) {
  const int*   X  = (const int*)d_in[0];
  const float* w1 = (const float*)d_in[1];
  const float* b1 = (const float*)d_in[2];
  const float* w2 = (const float*)d_in[3];
  const float* b2 = (const float*)d_in[4];
  const float* w3 = (const float*)d_in[5];
  const float* b3 = (const float*)d_in[6];

  float* out   = (float*)d_out;
  float* A_out = out;                           // (B,H,W,K) f32
  float* T_out = out + (size_t)NPIX * KK;       // (B,K,17)

  char*  ws   = (char*)d_ws;
  f16*   bufA = (f16*)ws;                                   // 32 MB planes (A after iter 4)
  float* wb   = (float*)(ws + (size_t)32*1024*1024);        // 8 MB (pre-scaled w')
  float* part = (float*)ws;                                 // aliases bufA (dead at pool time)

  cnnaff_kernel<<<dim3(WD/32, HD/16, BB), 512, 0, stream>>>(X, w1, b1, w2, b2, w3, b3, wb);

  mp4_kernel<1,0><<<1024, 512, 0, stream>>>(nullptr, wb, bufA, nullptr);  // iters 1-4 (analytic A0)
  mp4_kernel<0,1><<<1024, 512, 0, stream>>>(bufA, wb, nullptr, A_out);    // iters 5-8 -> f32 canonical

  pool1_kernel<<<dim3(BB, 32), 256, 0, stream>>>(A_out, X, part);
  pool2_kernel<<<(BB*KK + 255)/256, 256, 0, stream>>>(part, T_out);
}

// Round 11
// 234.185 us; speedup vs baseline: 1.0746x; 1.0746x over previous
//
#include <hip/hip_runtime.h>
#include <math.h>

#define HD 128
#define WD 128
#define BB 32
#define KK 32
#define NPIX (BB*HD*WD)   // 524288
#define PLANE ((size_t)NPIX*8)   // f16 elems per plane

typedef _Float16 f16;
typedef __attribute__((ext_vector_type(8))) _Float16 f16x8;
typedef __attribute__((ext_vector_type(4))) _Float16 f16x4;
typedef __attribute__((ext_vector_type(4))) float f32x4;

// byte offset of 16B chunk g within 64B row; bijective over (row mod 8) -> all 32 banks
__device__ __forceinline__ int swz(int row, int g){
  return row*64 + (((g + (row >> 1)) & 3) << 4);
}

__device__ __forceinline__ float xexp2(float x){
#if __has_builtin(__builtin_amdgcn_exp2f)
  return __builtin_amdgcn_exp2f(x);
#else
  return exp2f(x);
#endif
}
__device__ __forceinline__ float xrcp(float x){
#if __has_builtin(__builtin_amdgcn_rcpf)
  return __builtin_amdgcn_rcpf(x);
#else
  return 1.f/x;
#endif
}
__device__ __forceinline__ f16x8 bc8(f16 x){
  f16x8 v;
  #pragma unroll
  for (int j = 0; j < 8; j++) v[j] = x;
  return v;
}

#define WSCALE 2.8853900817779268f   // 2*log2(e)

// ---------------- fused CNN via f16 MFMA (R6 version, 41.5 us) ----------------
__global__ __launch_bounds__(512, 2) void cnn_kernel(
    const int* __restrict__ X,
    const float* __restrict__ w1, const float* __restrict__ b1,
    const float* __restrict__ w2, const float* __restrict__ b2,
    const float* __restrict__ w3, const float* __restrict__ b3,
    f16* __restrict__ phi)
{
  __shared__ f16 sW1f[9*11*40];
  __shared__ int   sX[20*36];
  __shared__ float sB2[32], sB3[32];
  __shared__ f16 x1[612*32];
  __shared__ f16 w2t[9*32*32];
  __shared__ f16 w3t[32*32];

  const int tid = threadIdx.x;
  const int img = blockIdx.z;
  const int bh0 = blockIdx.y * 16;
  const int bw0 = blockIdx.x * 32;

  for (int i = tid; i < 9*11*32; i += 512) {
    int tap = i / 352, c = (i % 352) >> 5, oc = i & 31;
    float v = (c < 10) ? w1[tap*320 + c*32 + oc] : 0.f;
    if (tap == 4 && c < 10) v += b1[oc];
    sW1f[(tap*11 + c)*40 + oc] = (f16)v;
  }
  for (int i = tid; i < 9*32*32; i += 512) {
    int tap = i >> 10, ic = (i >> 5) & 31, oc = i & 31;
    int off = swz(tap*32 + oc, ic >> 3) + (ic & 7)*2;
    *(f16*)((char*)w2t + off) = (f16)w2[i];
  }
  for (int i = tid; i < 32*32; i += 512) {
    int ic = i >> 5, oe = i & 31;
    int off = swz(oe, ic >> 3) + (ic & 7)*2;
    *(f16*)((char*)w3t + off) = (f16)w3[i];
  }
  if (tid < 32) { sB2[tid] = b2[tid]; sB3[tid] = b3[tid]; }
  for (int i = tid; i < 20*36; i += 512) {
    int ti = i / 36, tj = i % 36;
    int gh = bh0 - 2 + ti, gw = bw0 - 2 + tj;
    sX[i] = (gh >= 0 && gh < HD && gw >= 0 && gw < WD) ? X[(img*HD + gh)*WD + gw] : 10;
  }
  __syncthreads();

  for (int p = tid; p < 612; p += 512) {
    int hr = p / 34, hc = p - hr*34;
    int gh = bh0 + hr - 1, gw = bw0 + hc - 1;
    if (gh >= 0 && gh < HD && gw >= 0 && gw < WD) {
      f16x8 acc[4];
      {
        int c = sX[hr*36 + hc];
        const f16* wr = &sW1f[c*40];
        #pragma unroll
        for (int g = 0; g < 4; g++) acc[g] = *(const f16x8*)(wr + g*8);
      }
      #pragma unroll
      for (int tap = 1; tap < 9; tap++) {
        const int ti = tap/3, tj = tap%3;
        int c = sX[(hr+ti)*36 + hc + tj];
        const f16* wr = &sW1f[(tap*11 + c)*40];
        #pragma unroll
        for (int g = 0; g < 4; g++) acc[g] += *(const f16x8*)(wr + g*8);
      }
      #pragma unroll
      for (int g = 0; g < 4; g++) {
        f16x8 r = acc[g];
        #pragma unroll
        for (int j = 0; j < 8; j++) r[j] = (r[j] > (f16)0.f) ? r[j] : (f16)0.f;
        *(f16x8*)((char*)x1 + swz(p, g)) = r;
      }
    } else {
      f16x8 z;
      #pragma unroll
      for (int j = 0; j < 8; j++) z[j] = (f16)0.f;
      #pragma unroll
      for (int g = 0; g < 4; g++) *(f16x8*)((char*)x1 + swz(p, g)) = z;
    }
  }
  __syncthreads();

  const int lane = tid & 63;
  const int wv   = tid >> 6;
  const int lr   = lane & 15;
  const int kg   = lane >> 4;
  const int mts  = wv * 4;

  int arow0[4];
  #pragma unroll
  for (int q = 0; q < 4; q++) {
    int px = (mts + q)*16 + lr;
    arow0[q] = (px >> 5)*34 + (px & 31);
  }
  float b2v0 = sB2[lr], b2v1 = sB2[lr + 16];
  f32x4 acc[4][2];
  #pragma unroll
  for (int q = 0; q < 4; q++) {
    acc[q][0] = (f32x4){b2v0, b2v0, b2v0, b2v0};
    acc[q][1] = (f32x4){b2v1, b2v1, b2v1, b2v1};
  }
  #pragma unroll
  for (int tap = 0; tap < 9; tap++) {
    const int ti = tap/3, tj = tap%3;
    f16x8 bf0 = *(const f16x8*)((const char*)w2t + swz(tap*32 + lr,      kg));
    f16x8 bf1 = *(const f16x8*)((const char*)w2t + swz(tap*32 + lr + 16, kg));
    #pragma unroll
    for (int q = 0; q < 4; q++) {
      int row = arow0[q] + ti*34 + tj;
      f16x8 af = *(const f16x8*)((const char*)x1 + swz(row, kg));
      acc[q][0] = __builtin_amdgcn_mfma_f32_16x16x32_f16(af, bf0, acc[q][0], 0, 0, 0);
      acc[q][1] = __builtin_amdgcn_mfma_f32_16x16x32_f16(af, bf1, acc[q][1], 0, 0, 0);
    }
  }
  __syncthreads();

  #pragma unroll
  for (int q = 0; q < 4; q++)
    #pragma unroll
    for (int nt = 0; nt < 2; nt++) {
      int oc = nt*16 + lr;
      #pragma unroll
      for (int rg = 0; rg < 4; rg++) {
        int px = (mts + q)*16 + kg*4 + rg;
        int off = swz(px, oc >> 3) + (oc & 7)*2;
        *(f16*)((char*)x1 + off) = (f16)fmaxf(acc[q][nt][rg], 0.f);
      }
    }
  __syncthreads();

  {
    f16x8 cf0 = *(const f16x8*)((const char*)w3t + swz(lr,      kg));
    f16x8 cf1 = *(const f16x8*)((const char*)w3t + swz(lr + 16, kg));
    float b3v0 = sB3[lr], b3v1 = sB3[lr + 16];
    #pragma unroll
    for (int q = 0; q < 4; q++) {
      f16x8 af = *(const f16x8*)((const char*)x1 + swz((mts + q)*16 + lr, kg));
      f32x4 o0 = (f32x4){b3v0, b3v0, b3v0, b3v0};
      f32x4 o1 = (f32x4){b3v1, b3v1, b3v1, b3v1};
      o0 = __builtin_amdgcn_mfma_f32_16x16x32_f16(af, cf0, o0, 0, 0, 0);
      o1 = __builtin_amdgcn_mfma_f32_16x16x32_f16(af, cf1, o1, 0, 0, 0);
      #pragma unroll
      for (int rg = 0; rg < 4; rg++) {
        int px = (mts + q)*16 + kg*4 + rg;
        int gh = bh0 + (px >> 5), gw = bw0 + (px & 31);
        f16* dst = phi + ((size_t)((img*HD + gh)*WD + gw))*32;
        dst[lr]      = (f16)o0[rg];
        dst[lr + 16] = (f16)o1[rg];
      }
    }
  }
}

// ---------------- neighbor affinity, LDS-tiled (R7 version); outputs w' = 2*log2e*exp(-2*d2) ----------------
__device__ __forceinline__ float aff_lds(const f16* __restrict__ sphi, int slot,
                                         f16x8 c0, f16x8 c1, f16x8 c2, f16x8 c3,
                                         bool valid) {
  f16x8 n0 = *(const f16x8*)((const char*)sphi + swz(slot, 0));
  f16x8 n1 = *(const f16x8*)((const char*)sphi + swz(slot, 1));
  f16x8 n2 = *(const f16x8*)((const char*)sphi + swz(slot, 2));
  f16x8 n3 = *(const f16x8*)((const char*)sphi + swz(slot, 3));
  f16x8 d0 = c0 - n0; f16x8 s = d0*d0;
  f16x8 d1 = c1 - n1; s += d1*d1;
  f16x8 d2 = c2 - n2; s += d2*d2;
  f16x8 d3 = c3 - n3; s += d3*d3;
  float d2f = 0.f;
  #pragma unroll
  for (int j = 0; j < 8; j++) d2f += (float)s[j];
  return valid ? WSCALE * xexp2(-WSCALE * d2f) : 0.f;
}

__global__ __launch_bounds__(256, 4) void aff_kernel(const f16* __restrict__ phi, float* __restrict__ wb) {
  __shared__ f16 sphi[612*32];

  const int blk  = blockIdx.x;          // 1024
  const int tile = blk & 31;
  const int img  = blk >> 5;
  const int th0  = (tile >> 2) * 16;
  const int tw0  = (tile & 3) * 32;
  const size_t ibase = (size_t)img * HD * WD;

  for (int task = threadIdx.x; task < 2448; task += 256) {
    int p = task >> 2, g = task & 3;
    int r = p / 34, c = p - r*34;
    int gh = min(max(th0 - 1 + r, 0), HD-1);
    int gw = min(max(tw0 - 1 + c, 0), WD-1);
    f16x8 v = *(const f16x8*)(phi + (ibase + gh*WD + gw)*32 + g*8);
    *(f16x8*)((char*)sphi + swz(p, g)) = v;
  }
  __syncthreads();

  for (int p2 = threadIdx.x; p2 < 512; p2 += 256) {
    int r2 = p2 >> 5, c2 = p2 & 31;
    int gh = th0 + r2, gw = tw0 + c2;
    int qc = (r2+1)*34 + (c2+1);
    f16x8 c0 = *(const f16x8*)((const char*)sphi + swz(qc, 0));
    f16x8 c1 = *(const f16x8*)((const char*)sphi + swz(qc, 1));
    f16x8 c2v = *(const f16x8*)((const char*)sphi + swz(qc, 2));
    f16x8 c3 = *(const f16x8*)((const char*)sphi + swz(qc, 3));
    float4 out;
    out.x = aff_lds(sphi, qc + 34, c0,c1,c2v,c3, gh < HD-1);
    out.y = aff_lds(sphi, qc - 34, c0,c1,c2v,c3, gh > 0);
    out.z = aff_lds(sphi, qc + 1,  c0,c1,c2v,c3, gw < WD-1);
    out.w = aff_lds(sphi, qc - 1,  c0,c1,c2v,c3, gw > 0);
    ((float4*)wb)[ibase + gh*WD + gw] = out;
  }
}

// ---------------- analytic A0 accumulate (separable) ----------------
__device__ __forceinline__ void a0_accum2(float* a, int hh, int ww, float wt) {
  const float C = 0.0028177637517362567f;  // log2(e)/512
  float eh[4], ew[8];
  float sh = 0.f, sw = 0.f;
  const float fh = (float)hh, fw = (float)ww;
  #pragma unroll
  for (int kh = 0; kh < 4; kh++) { float d = fh - (float)(kh*32+16); eh[kh] = xexp2(-d*d*C); sh += eh[kh]; }
  #pragma unroll
  for (int kw = 0; kw < 8; kw++) { float d = fw - (float)(kw*16+8); ew[kw] = xexp2(-d*d*C); sw += ew[kw]; }
  float sc = wt * xrcp(sh * sw);
  #pragma unroll
  for (int kh = 0; kh < 4; kh++) {
    float ehs = eh[kh] * sc;
    #pragma unroll
    for (int kw = 0; kw < 8; kw++) a[kh*8+kw] = fmaf(ehs, ew[kw], a[kh*8+kw]);
  }
}

// ---------------- fused message-pass pair (R9 structure); plane-major output ----------------
template<int FIRST>
__global__ __launch_bounds__(512, 6) void mp2_kernel(const f16* __restrict__ Ain,
                                                     const float* __restrict__ wb,
                                                     f16* __restrict__ Aout) {
  __shared__ f16 amid[612*32];

  const int blk  = blockIdx.x;          // 1024
  const int xcd  = blk & 7;
  const int q    = blk >> 3;
  const int img  = xcd + ((q >> 5) << 3);
  const int tile = q & 31;
  const int th0  = (tile >> 2) * 16;
  const int tw0  = (tile & 3) * 32;
  const size_t ibase = (size_t)img * HD * WD;

  for (int p = threadIdx.x; p < 612; p += 512) {
    int r = p / 34, cc = p - r*34;
    int gh = th0 - 1 + r, gw = tw0 - 1 + cc;
    bool inimg = ((unsigned)gh < (unsigned)HD) && ((unsigned)gw < (unsigned)WD);
    int ghc = min(max(gh, 0), HD-1), gwc = min(max(gw, 0), WD-1);
    float4 wd = inimg ? ((const float4*)wb)[ibase + gh*WD + gw] : make_float4(0.f,0.f,0.f,0.f);
    int hu = ghc + ((ghc < HD-1) ? 1 : 0);
    int hd = ghc - ((ghc > 0)    ? 1 : 0);
    int wl = gwc + ((gwc < WD-1) ? 1 : 0);
    int wr = gwc - ((gwc > 0)    ? 1 : 0);

    float s = 0.f;
    f16x8 pe[4];
    if (FIRST) {
      float a[32];
      #pragma unroll
      for (int k = 0; k < 32; k++) a[k] = 0.f;
      a0_accum2(a, hu, gwc, wd.x);
      a0_accum2(a, hd, gwc, wd.y);
      a0_accum2(a, ghc, wl, wd.z);
      a0_accum2(a, ghc, wr, wd.w);
      #pragma unroll
      for (int g = 0; g < 4; g++)
        #pragma unroll
        for (int j = 0; j < 8; j++) { float e = xexp2(a[g*8+j]); s += e; pe[g][j] = (f16)e; }
    } else {
      const size_t iu_ = ibase + (size_t)hu*WD + gwc;
      const size_t id_ = ibase + (size_t)hd*WD + gwc;
      const size_t il_ = ibase + (size_t)ghc*WD + wl;
      const size_t ir_ = ibase + (size_t)ghc*WD + wr;
      f16x8 w0 = bc8((f16)wd.x), w1 = bc8((f16)wd.y), w2 = bc8((f16)wd.z), w3 = bc8((f16)wd.w);
      #pragma unroll
      for (int g = 0; g < 4; g++) {
        const f16* pg = Ain + (size_t)g*PLANE;
        f16x8 v0 = *(const f16x8*)(pg + iu_*8);
        f16x8 v1 = *(const f16x8*)(pg + id_*8);
        f16x8 v2 = *(const f16x8*)(pg + il_*8);
        f16x8 v3 = *(const f16x8*)(pg + ir_*8);
        f16x8 agg = v0*w0 + v1*w1 + v2*w2 + v3*w3;
        #pragma unroll
        for (int j = 0; j < 8; j++) { float e = xexp2((float)agg[j]); s += e; pe[g][j] = (f16)e; }
      }
    }
    f16x8 iv = bc8((f16)xrcp(s));
    #pragma unroll
    for (int g = 0; g < 4; g++)
      *(f16x8*)((char*)amid + swz(p, g)) = pe[g]*iv;
  }
  __syncthreads();

  {
    int r2 = threadIdx.x >> 5, c2 = threadIdx.x & 31;
    int gh = th0 + r2, gw = tw0 + c2;
    int rm = r2 + 1, cm = c2 + 1;
    float4 wd = ((const float4*)wb)[ibase + gh*WD + gw];
    int q0 = (rm + ((gh < HD-1) ? 1 : 0))*34 + cm;
    int q1 = (rm - ((gh > 0)    ? 1 : 0))*34 + cm;
    int q2 = rm*34 + cm + ((gw < WD-1) ? 1 : 0);
    int q3 = rm*34 + cm - ((gw > 0)    ? 1 : 0);
    f16x8 w0 = bc8((f16)wd.x), w1 = bc8((f16)wd.y), w2 = bc8((f16)wd.z), w3 = bc8((f16)wd.w);
    float s = 0.f;
    f16x8 pe[4];
    #pragma unroll
    for (int g = 0; g < 4; g++) {
      f16x8 v0 = *(const f16x8*)((const char*)amid + swz(q0, g));
      f16x8 v1 = *(const f16x8*)((const char*)amid + swz(q1, g));
      f16x8 v2 = *(const f16x8*)((const char*)amid + swz(q2, g));
      f16x8 v3 = *(const f16x8*)((const char*)amid + swz(q3, g));
      f16x8 agg = v0*w0 + v1*w1 + v2*w2 + v3*w3;
      #pragma unroll
      for (int j = 0; j < 8; j++) { float e = xexp2((float)agg[j]); s += e; pe[g][j] = (f16)e; }
    }
    f16x8 iv = bc8((f16)xrcp(s));
    size_t opix = ibase + (size_t)gh*WD + gw;
    #pragma unroll
    for (int g = 0; g < 4; g++)
      *(f16x8*)(Aout + (size_t)g*PLANE + opix*8) = pe[g]*iv;
  }
}

// ---------------- LAST mp2: iters 7,8 + coalesced f32 A write + fused pool partials ----------------
__global__ __launch_bounds__(512, 2) void mp2last_kernel(const f16* __restrict__ Ain,
                                                         const float* __restrict__ wb,
                                                         const int* __restrict__ X,
                                                         float* __restrict__ AoutF,
                                                         float* __restrict__ part) {
  __shared__ f16 amid[612*32];          // phase A/B stencil buffer; reused as planes
  __shared__ float red[16*33*15];       // [g(row)][33-pad k][15]
  __shared__ int sXt[512];

  const int blk  = blockIdx.x;          // 1024
  const int xcd  = blk & 7;
  const int q    = blk >> 3;
  const int img  = xcd + ((q >> 5) << 3);
  const int tile = q & 31;
  const int th0  = (tile >> 2) * 16;
  const int tw0  = (tile & 3) * 32;
  const size_t ibase = (size_t)img * HD * WD;

  // stage X tile (coalesced)
  {
    int r = threadIdx.x >> 5, c = threadIdx.x & 31;
    sXt[threadIdx.x] = X[ibase + (size_t)(th0 + r)*WD + tw0 + c];
  }

  // ---- phase A: amid 18x34 (iter 7) ----
  for (int p = threadIdx.x; p < 612; p += 512) {
    int r = p / 34, cc = p - r*34;
    int gh = th0 - 1 + r, gw = tw0 - 1 + cc;
    bool inimg = ((unsigned)gh < (unsigned)HD) && ((unsigned)gw < (unsigned)WD);
    int ghc = min(max(gh, 0), HD-1), gwc = min(max(gw, 0), WD-1);
    float4 wd = inimg ? ((const float4*)wb)[ibase + gh*WD + gw] : make_float4(0.f,0.f,0.f,0.f);
    int hu = ghc + ((ghc < HD-1) ? 1 : 0);
    int hd = ghc - ((ghc > 0)    ? 1 : 0);
    int wl = gwc + ((gwc < WD-1) ? 1 : 0);
    int wr = gwc - ((gwc > 0)    ? 1 : 0);

    const size_t iu_ = ibase + (size_t)hu*WD + gwc;
    const size_t id_ = ibase + (size_t)hd*WD + gwc;
    const size_t il_ = ibase + (size_t)ghc*WD + wl;
    const size_t ir_ = ibase + (size_t)ghc*WD + wr;
    f16x8 w0 = bc8((f16)wd.x), w1 = bc8((f16)wd.y), w2 = bc8((f16)wd.z), w3 = bc8((f16)wd.w);
    float s = 0.f;
    f16x8 pe[4];
    #pragma unroll
    for (int g = 0; g < 4; g++) {
      const f16* pg = Ain + (size_t)g*PLANE;
      f16x8 v0 = *(const f16x8*)(pg + iu_*8);
      f16x8 v1 = *(const f16x8*)(pg + id_*8);
      f16x8 v2 = *(const f16x8*)(pg + il_*8);
      f16x8 v3 = *(const f16x8*)(pg + ir_*8);
      f16x8 agg = v0*w0 + v1*w1 + v2*w2 + v3*w3;
      #pragma unroll
      for (int j = 0; j < 8; j++) { float e = xexp2((float)agg[j]); s += e; pe[g][j] = (f16)e; }
    }
    f16x8 iv = bc8((f16)xrcp(s));
    #pragma unroll
    for (int g = 0; g < 4; g++)
      *(f16x8*)((char*)amid + swz(p, g)) = pe[g]*iv;
  }
  __syncthreads();

  // ---- phase B: interior 16x32 (iter 8), pe in registers ----
  f16x8 pe[4];
  {
    int r2 = threadIdx.x >> 5, c2 = threadIdx.x & 31;
    int gh = th0 + r2, gw = tw0 + c2;
    int rm = r2 + 1, cm = c2 + 1;
    float4 wd = ((const float4*)wb)[ibase + gh*WD + gw];
    int q0 = (rm + ((gh < HD-1) ? 1 : 0))*34 + cm;
    int q1 = (rm - ((gh > 0)    ? 1 : 0))*34 + cm;
    int q2 = rm*34 + cm + ((gw < WD-1) ? 1 : 0);
    int q3 = rm*34 + cm - ((gw > 0)    ? 1 : 0);
    f16x8 w0 = bc8((f16)wd.x), w1 = bc8((f16)wd.y), w2 = bc8((f16)wd.z), w3 = bc8((f16)wd.w);
    float s = 0.f;
    #pragma unroll
    for (int g = 0; g < 4; g++) {
      f16x8 v0 = *(const f16x8*)((const char*)amid + swz(q0, g));
      f16x8 v1 = *(const f16x8*)((const char*)amid + swz(q1, g));
      f16x8 v2 = *(const f16x8*)((const char*)amid + swz(q2, g));
      f16x8 v3 = *(const f16x8*)((const char*)amid + swz(q3, g));
      f16x8 agg = v0*w0 + v1*w1 + v2*w2 + v3*w3;
      #pragma unroll
      for (int j = 0; j < 8; j++) { float e = xexp2((float)agg[j]); s += e; pe[g][j] = (f16)e; }
    }
    f16x8 iv = bc8((f16)xrcp(s));
    #pragma unroll
    for (int g = 0; g < 4; g++) pe[g] = pe[g]*iv;
  }

  // ---- phase C: planes to LDS, coalesced f32 A write ----
  __syncthreads();                       // amid reads complete
  f16* planes = amid;
  #pragma unroll
  for (int g = 0; g < 4; g++)
    *(f16x8*)((char*)planes + (g*513 + threadIdx.x)*16) = pe[g];
  __syncthreads();
  {
    float* obase = AoutF + ((size_t)(img*HD + th0)*WD + tw0)*32;
    #pragma unroll
    for (int rep = 0; rep < 8; rep++) {
      int flat = rep*512 + threadIdx.x;
      int row = flat >> 8;
      int within = flat & 255;
      int pxr = within >> 3;
      int kq = within & 7;
      int g = kq >> 1, half = kq & 1;
      int pxl = row*32 + pxr;
      f16x4 v = *(const f16x4*)((const char*)planes + (g*513 + pxl)*16 + half*8);
      float4 o;
      o.x = (float)v[0]; o.y = (float)v[1]; o.z = (float)v[2]; o.w = (float)v[3];
      *(float4*)(obase + (size_t)row*WD*32 + pxr*32 + kq*4) = o;
    }
  }

  // ---- phase D: pooled partials per tile: thread (k = t&31, row g = t>>5) ----
  {
    const int k  = threadIdx.x & 31;
    const int gr = threadIdx.x >> 5;       // 0..15
    const int gq = k >> 3, j = k & 7;
    const float hh = ((float)(th0 + gr) + 0.5f) * (1.f/128.f);
    float s0 = 0.f, sw = 0.f, sw2 = 0.f;
    float col[10];
    #pragma unroll
    for (int c = 0; c < 10; c++) col[c] = 0.f;
    #pragma unroll
    for (int i = 0; i < 32; i++) {
      int px = gr*32 + i;
      float a = (float)*(const f16*)((const char*)planes + (gq*513 + px)*16 + j*2);
      float ww = ((float)(tw0 + i) + 0.5f) * (1.f/128.f);
      s0 += a; sw = fmaf(ww, a, sw); sw2 = fmaf(ww*ww, a, sw2);
      int x = sXt[px];
      #pragma unroll
      for (int c = 0; c < 10; c++) col[c] += (x == c) ? a : 0.f;
    }
    float* rd = &red[(gr*33 + k)*15];
    rd[0] = s0; rd[1] = hh*s0; rd[2] = sw; rd[3] = hh*hh*s0; rd[4] = sw2;
    #pragma unroll
    for (int c = 0; c < 10; c++) rd[5+c] = col[c];
  }
  __syncthreads();
  // reduce over 16 rows -> part[img][tile][k][15]
  if (threadIdx.x < 480) {
    int k = threadIdx.x / 15, qq = threadIdx.x - k*15;
    float v = 0.f;
    #pragma unroll
    for (int g = 0; g < 16; g++) v += red[(g*33 + k)*15 + qq];
    part[(((size_t)img*32 + tile)*32 + k)*15 + qq] = v;
  }
}

// ---------------- pooled features, stage 2 ----------------
__global__ __launch_bounds__(256) void pool2_kernel(const float* __restrict__ part,
                                                    float* __restrict__ T) {
  const int t = blockIdx.x * 256 + threadIdx.x;
  if (t >= BB*KK) return;
  const int b = t >> 5, k = t & 31;
  float s[15];
  #pragma unroll
  for (int q = 0; q < 15; q++) s[q] = 0.f;
  for (int cy = 0; cy < 32; cy++) {
    const float* p = part + (((size_t)b*32 + cy)*32 + k)*15;
    #pragma unroll
    for (int q = 0; q < 15; q++) s[q] += p[q];
  }
  float mass = s[0] + 1e-6f;
  float inv  = 1.f / mass;
  float h_c = s[1]*inv, w_c = s[2]*inv, h2 = s[3]*inv, w2 = s[4]*inv;
  float h_sd = sqrtf(fmaxf(h2 - h_c*h_c, 0.f) + 1e-6f);
  float w_sd = sqrtf(fmaxf(w2 - w_c*w_c, 0.f) + 1e-6f);
  float* o = T + (size_t)t*17;
  o[0] = mass * (1.f/16384.f);
  o[1] = h_c; o[2] = w_c;
  #pragma unroll
  for (int c = 0; c < 10; c++) o[3+c] = s[5+c]*inv;
  o[13] = h_c - h_sd; o[14] = h_c + h_sd; o[15] = w_c - w_sd; o[16] = w_c + w_sd;
}

extern "C" void kernel_launch(void* const* d_in, const int* in_sizes, int n_in,
                              void* d_out, int out_size, void* d_ws, size_t ws_size,
                              hipStream_t stream) {
  const int*   X  = (const int*)d_in[0];
  const float* w1 = (const float*)d_in[1];
  const float* b1 = (const float*)d_in[2];
  const float* w2 = (const float*)d_in[3];
  const float* b2 = (const float*)d_in[4];
  const float* w3 = (const float*)d_in[5];
  const float* b3 = (const float*)d_in[6];

  float* out   = (float*)d_out;
  float* A_out = out;                           // (B,H,W,K) f32
  float* T_out = out + (size_t)NPIX * KK;       // (B,K,17)

  char*  ws   = (char*)d_ws;
  f16*   bufA = (f16*)ws;                                   // 32 MB planes (ping)
  f16*   bufB = (f16*)(ws + (size_t)32*1024*1024);          // 32 MB planes (pong); phi first
  float* wb   = (float*)(ws + (size_t)64*1024*1024);        // 8 MB (pre-scaled w')
  float* part = (float*)(ws + (size_t)72*1024*1024);        // ~2 MB

  f16* phi = bufB;
  cnn_kernel<<<dim3(WD/32, HD/16, BB), 512, 0, stream>>>(X, w1, b1, w2, b2, w3, b3, phi);
  aff_kernel<<<1024, 256, 0, stream>>>(phi, wb);

  mp2_kernel<1><<<1024, 512, 0, stream>>>(nullptr, wb, bufA);          // iters 1,2 (analytic A0)
  mp2_kernel<0><<<1024, 512, 0, stream>>>(bufA, wb, bufB);             // iters 3,4
  mp2_kernel<0><<<1024, 512, 0, stream>>>(bufB, wb, bufA);             // iters 5,6
  mp2last_kernel<<<1024, 512, 0, stream>>>(bufA, wb, X, A_out, part);  // iters 7,8 + pool partials

  pool2_kernel<<<(BB*KK + 255)/256, 256, 0, stream>>>(part, T_out);
}

// Round 12
// 232.654 us; speedup vs baseline: 1.0816x; 1.0066x over previous
//
#include <hip/hip_runtime.h>
#include <math.h>

#define HD 128
#define WD 128
#define BB 32
#define KK 32
#define NPIX (BB*HD*WD)   // 524288
#define PLANE ((size_t)NPIX*8)   // f16 elems per plane

typedef _Float16 f16;
typedef __attribute__((ext_vector_type(8))) _Float16 f16x8;
typedef __attribute__((ext_vector_type(4))) _Float16 f16x4;
typedef __attribute__((ext_vector_type(4))) float f32x4;

// byte offset of 16B chunk g within 64B row; bijective over (row mod 8) -> all 32 banks
__device__ __forceinline__ int swz(int row, int g){
  return row*64 + (((g + (row >> 1)) & 3) << 4);
}

__device__ __forceinline__ float xexp2(float x){
#if __has_builtin(__builtin_amdgcn_exp2f)
  return __builtin_amdgcn_exp2f(x);
#else
  return exp2f(x);
#endif
}
__device__ __forceinline__ float xrcp(float x){
#if __has_builtin(__builtin_amdgcn_rcpf)
  return __builtin_amdgcn_rcpf(x);
#else
  return 1.f/x;
#endif
}
__device__ __forceinline__ f16x8 bc8(f16 x){
  f16x8 v;
  #pragma unroll
  for (int j = 0; j < 8; j++) v[j] = x;
  return v;
}

#define WSCALE 2.8853900817779268f   // 2*log2(e)

// ---------------- fused CNN via f16 MFMA (R6 version) ----------------
__global__ __launch_bounds__(512, 2) void cnn_kernel(
    const int* __restrict__ X,
    const float* __restrict__ w1, const float* __restrict__ b1,
    const float* __restrict__ w2, const float* __restrict__ b2,
    const float* __restrict__ w3, const float* __restrict__ b3,
    f16* __restrict__ phi)
{
  __shared__ f16 sW1f[9*11*40];
  __shared__ int   sX[20*36];
  __shared__ float sB2[32], sB3[32];
  __shared__ f16 x1[612*32];
  __shared__ f16 w2t[9*32*32];
  __shared__ f16 w3t[32*32];

  const int tid = threadIdx.x;
  const int img = blockIdx.z;
  const int bh0 = blockIdx.y * 16;
  const int bw0 = blockIdx.x * 32;

  for (int i = tid; i < 9*11*32; i += 512) {
    int tap = i / 352, c = (i % 352) >> 5, oc = i & 31;
    float v = (c < 10) ? w1[tap*320 + c*32 + oc] : 0.f;
    if (tap == 4 && c < 10) v += b1[oc];
    sW1f[(tap*11 + c)*40 + oc] = (f16)v;
  }
  for (int i = tid; i < 9*32*32; i += 512) {
    int tap = i >> 10, ic = (i >> 5) & 31, oc = i & 31;
    int off = swz(tap*32 + oc, ic >> 3) + (ic & 7)*2;
    *(f16*)((char*)w2t + off) = (f16)w2[i];
  }
  for (int i = tid; i < 32*32; i += 512) {
    int ic = i >> 5, oe = i & 31;
    int off = swz(oe, ic >> 3) + (ic & 7)*2;
    *(f16*)((char*)w3t + off) = (f16)w3[i];
  }
  if (tid < 32) { sB2[tid] = b2[tid]; sB3[tid] = b3[tid]; }
  for (int i = tid; i < 20*36; i += 512) {
    int ti = i / 36, tj = i % 36;
    int gh = bh0 - 2 + ti, gw = bw0 - 2 + tj;
    sX[i] = (gh >= 0 && gh < HD && gw >= 0 && gw < WD) ? X[(img*HD + gh)*WD + gw] : 10;
  }
  __syncthreads();

  for (int p = tid; p < 612; p += 512) {
    int hr = p / 34, hc = p - hr*34;
    int gh = bh0 + hr - 1, gw = bw0 + hc - 1;
    if (gh >= 0 && gh < HD && gw >= 0 && gw < WD) {
      f16x8 acc[4];
      {
        int c = sX[hr*36 + hc];
        const f16* wr = &sW1f[c*40];
        #pragma unroll
        for (int g = 0; g < 4; g++) acc[g] = *(const f16x8*)(wr + g*8);
      }
      #pragma unroll
      for (int tap = 1; tap < 9; tap++) {
        const int ti = tap/3, tj = tap%3;
        int c = sX[(hr+ti)*36 + hc + tj];
        const f16* wr = &sW1f[(tap*11 + c)*40];
        #pragma unroll
        for (int g = 0; g < 4; g++) acc[g] += *(const f16x8*)(wr + g*8);
      }
      #pragma unroll
      for (int g = 0; g < 4; g++) {
        f16x8 r = acc[g];
        #pragma unroll
        for (int j = 0; j < 8; j++) r[j] = (r[j] > (f16)0.f) ? r[j] : (f16)0.f;
        *(f16x8*)((char*)x1 + swz(p, g)) = r;
      }
    } else {
      f16x8 z;
      #pragma unroll
      for (int j = 0; j < 8; j++) z[j] = (f16)0.f;
      #pragma unroll
      for (int g = 0; g < 4; g++) *(f16x8*)((char*)x1 + swz(p, g)) = z;
    }
  }
  __syncthreads();

  const int lane = tid & 63;
  const int wv   = tid >> 6;
  const int lr   = lane & 15;
  const int kg   = lane >> 4;
  const int mts  = wv * 4;

  int arow0[4];
  #pragma unroll
  for (int q = 0; q < 4; q++) {
    int px = (mts + q)*16 + lr;
    arow0[q] = (px >> 5)*34 + (px & 31);
  }
  float b2v0 = sB2[lr], b2v1 = sB2[lr + 16];
  f32x4 acc[4][2];
  #pragma unroll
  for (int q = 0; q < 4; q++) {
    acc[q][0] = (f32x4){b2v0, b2v0, b2v0, b2v0};
    acc[q][1] = (f32x4){b2v1, b2v1, b2v1, b2v1};
  }
  #pragma unroll
  for (int tap = 0; tap < 9; tap++) {
    const int ti = tap/3, tj = tap%3;
    f16x8 bf0 = *(const f16x8*)((const char*)w2t + swz(tap*32 + lr,      kg));
    f16x8 bf1 = *(const f16x8*)((const char*)w2t + swz(tap*32 + lr + 16, kg));
    #pragma unroll
    for (int q = 0; q < 4; q++) {
      int row = arow0[q] + ti*34 + tj;
      f16x8 af = *(const f16x8*)((const char*)x1 + swz(row, kg));
      acc[q][0] = __builtin_amdgcn_mfma_f32_16x16x32_f16(af, bf0, acc[q][0], 0, 0, 0);
      acc[q][1] = __builtin_amdgcn_mfma_f32_16x16x32_f16(af, bf1, acc[q][1], 0, 0, 0);
    }
  }
  __syncthreads();

  #pragma unroll
  for (int q = 0; q < 4; q++)
    #pragma unroll
    for (int nt = 0; nt < 2; nt++) {
      int oc = nt*16 + lr;
      #pragma unroll
      for (int rg = 0; rg < 4; rg++) {
        int px = (mts + q)*16 + kg*4 + rg;
        int off = swz(px, oc >> 3) + (oc & 7)*2;
        *(f16*)((char*)x1 + off) = (f16)fmaxf(acc[q][nt][rg], 0.f);
      }
    }
  __syncthreads();

  {
    f16x8 cf0 = *(const f16x8*)((const char*)w3t + swz(lr,      kg));
    f16x8 cf1 = *(const f16x8*)((const char*)w3t + swz(lr + 16, kg));
    float b3v0 = sB3[lr], b3v1 = sB3[lr + 16];
    #pragma unroll
    for (int q = 0; q < 4; q++) {
      f16x8 af = *(const f16x8*)((const char*)x1 + swz((mts + q)*16 + lr, kg));
      f32x4 o0 = (f32x4){b3v0, b3v0, b3v0, b3v0};
      f32x4 o1 = (f32x4){b3v1, b3v1, b3v1, b3v1};
      o0 = __builtin_amdgcn_mfma_f32_16x16x32_f16(af, cf0, o0, 0, 0, 0);
      o1 = __builtin_amdgcn_mfma_f32_16x16x32_f16(af, cf1, o1, 0, 0, 0);
      #pragma unroll
      for (int rg = 0; rg < 4; rg++) {
        int px = (mts + q)*16 + kg*4 + rg;
        int gh = bh0 + (px >> 5), gw = bw0 + (px & 31);
        f16* dst = phi + ((size_t)((img*HD + gh)*WD + gw))*32;
        dst[lr]      = (f16)o0[rg];
        dst[lr + 16] = (f16)o1[rg];
      }
    }
  }
}

// ---------------- analytic A0 accumulate (separable) ----------------
__device__ __forceinline__ void a0_accum2(float* a, int hh, int ww, float wt) {
  const float C = 0.0028177637517362567f;  // log2(e)/512
  float eh[4], ew[8];
  float sh = 0.f, sw = 0.f;
  const float fh = (float)hh, fw = (float)ww;
  #pragma unroll
  for (int kh = 0; kh < 4; kh++) { float d = fh - (float)(kh*32+16); eh[kh] = xexp2(-d*d*C); sh += eh[kh]; }
  #pragma unroll
  for (int kw = 0; kw < 8; kw++) { float d = fw - (float)(kw*16+8); ew[kw] = xexp2(-d*d*C); sw += ew[kw]; }
  float sc = wt * xrcp(sh * sw);
  #pragma unroll
  for (int kh = 0; kh < 4; kh++) {
    float ehs = eh[kh] * sc;
    #pragma unroll
    for (int kw = 0; kw < 8; kw++) a[kh*8+kw] = fmaf(ehs, ew[kw], a[kh*8+kw]);
  }
}

// ---------------- fused affinity + mp iters 1,2 ----------------
// stage phi 20x36 -> aff wd on 18x34 (regs+LDS, interior to global wb) -> iter1 analytic -> amid -> iter2
__device__ __forceinline__ float aff36(const f16* __restrict__ sphi, int slot,
                                       f16x8 c0, f16x8 c1, f16x8 c2, f16x8 c3,
                                       bool valid) {
  if (!valid) return 0.f;
  f16x8 n0 = *(const f16x8*)((const char*)sphi + swz(slot, 0));
  f16x8 n1 = *(const f16x8*)((const char*)sphi + swz(slot, 1));
  f16x8 n2 = *(const f16x8*)((const char*)sphi + swz(slot, 2));
  f16x8 n3 = *(const f16x8*)((const char*)sphi + swz(slot, 3));
  f16x8 d0 = c0 - n0; f16x8 s = d0*d0;
  f16x8 d1 = c1 - n1; s += d1*d1;
  f16x8 d2 = c2 - n2; s += d2*d2;
  f16x8 d3 = c3 - n3; s += d3*d3;
  float d2f = 0.f;
  #pragma unroll
  for (int j = 0; j < 8; j++) d2f += (float)s[j];
  return WSCALE * xexp2(-WSCALE * d2f);
}

__global__ __launch_bounds__(512, 2) void affmp2_kernel(const f16* __restrict__ phi,
                                                        float* __restrict__ wb,
                                                        f16* __restrict__ Aout) {
  __shared__ f16 sphi[720*32];      // 20x36 phi frame; reused as amid (18x34) later
  __shared__ float4 wbs[612];       // wd per 18x34 px

  const int blk  = blockIdx.x;          // 1024
  const int xcd  = blk & 7;
  const int q    = blk >> 3;
  const int img  = xcd + ((q >> 5) << 3);
  const int tile = q & 31;
  const int th0  = (tile >> 2) * 16;
  const int tw0  = (tile & 3) * 32;
  const size_t ibase = (size_t)img * HD * WD;

  // ---- stage phi 20x36 (clamped) ----
  for (int task = threadIdx.x; task < 2880; task += 512) {
    int p = task >> 2, g = task & 3;
    int r = p / 36, c = p - r*36;
    int gh = min(max(th0 - 2 + r, 0), HD-1);
    int gw = min(max(tw0 - 2 + c, 0), WD-1);
    f16x8 v = *(const f16x8*)(phi + (ibase + (size_t)gh*WD + gw)*32 + g*8);
    *(f16x8*)((char*)sphi + swz(p, g)) = v;
  }
  __syncthreads();

  // ---- aff + iter1 into registers (2 slots/thread max) ----
  f16x8 res0[4], res1[4];
  const bool own1 = (threadIdx.x + 512) < 612;
  #pragma unroll
  for (int it = 0; it < 2; it++) {
    if (it == 1 && !own1) break;
    int p = threadIdx.x + it*512;
    int r = p / 34, cc = p - r*34;
    int gh = th0 - 1 + r, gw = tw0 - 1 + cc;
    bool inimg = ((unsigned)gh < (unsigned)HD) && ((unsigned)gw < (unsigned)WD);
    float4 wd = make_float4(0.f, 0.f, 0.f, 0.f);
    if (inimg) {
      int fs = (r + 1)*36 + (cc + 1);
      f16x8 c0 = *(const f16x8*)((const char*)sphi + swz(fs, 0));
      f16x8 c1 = *(const f16x8*)((const char*)sphi + swz(fs, 1));
      f16x8 c2 = *(const f16x8*)((const char*)sphi + swz(fs, 2));
      f16x8 c3 = *(const f16x8*)((const char*)sphi + swz(fs, 3));
      wd.x = aff36(sphi, fs + 36, c0,c1,c2,c3, gh < HD-1);
      wd.y = aff36(sphi, fs - 36, c0,c1,c2,c3, gh > 0);
      wd.z = aff36(sphi, fs + 1,  c0,c1,c2,c3, gw < WD-1);
      wd.w = aff36(sphi, fs - 1,  c0,c1,c2,c3, gw > 0);
    }
    wbs[p] = wd;
    if (r >= 1 && r <= 16 && cc >= 1 && cc <= 32)
      ((float4*)wb)[ibase + gh*WD + gw] = wd;

    // iter1: analytic A0 aggregation with wd
    int ghc = min(max(gh, 0), HD-1), gwc = min(max(gw, 0), WD-1);
    int hu = ghc + ((ghc < HD-1) ? 1 : 0);
    int hd = ghc - ((ghc > 0)    ? 1 : 0);
    int wl = gwc + ((gwc < WD-1) ? 1 : 0);
    int wr = gwc - ((gwc > 0)    ? 1 : 0);
    float a[32];
    #pragma unroll
    for (int k = 0; k < 32; k++) a[k] = 0.f;
    a0_accum2(a, hu, gwc, wd.x);
    a0_accum2(a, hd, gwc, wd.y);
    a0_accum2(a, ghc, wl, wd.z);
    a0_accum2(a, ghc, wr, wd.w);
    float s = 0.f;
    f16x8 pe[4];
    #pragma unroll
    for (int g = 0; g < 4; g++)
      #pragma unroll
      for (int j = 0; j < 8; j++) { float e = xexp2(a[g*8+j]); s += e; pe[g][j] = (f16)e; }
    f16x8 iv = bc8((f16)xrcp(s));
    #pragma unroll
    for (int g = 0; g < 4; g++) {
      if (it == 0) res0[g] = pe[g]*iv;
      else         res1[g] = pe[g]*iv;
    }
  }
  __syncthreads();   // all sphi reads done

  // ---- write amid (18x34 linear over sphi buffer) ----
  #pragma unroll
  for (int g = 0; g < 4; g++)
    *(f16x8*)((char*)sphi + swz(threadIdx.x, g)) = res0[g];
  if (own1) {
    #pragma unroll
    for (int g = 0; g < 4; g++)
      *(f16x8*)((char*)sphi + swz(threadIdx.x + 512, g)) = res1[g];
  }
  __syncthreads();

  // ---- iter2: interior 16x32 -> planes ----
  {
    int r2 = threadIdx.x >> 5, c2 = threadIdx.x & 31;
    int gh = th0 + r2, gw = tw0 + c2;
    int rm = r2 + 1, cm = c2 + 1;
    int pc_ = rm*34 + cm;
    float4 wd = wbs[pc_];
    int q0 = pc_ + ((gh < HD-1) ? 34 : 0);
    int q1 = pc_ - ((gh > 0)    ? 34 : 0);
    int q2 = pc_ + ((gw < WD-1) ? 1 : 0);
    int q3 = pc_ - ((gw > 0)    ? 1 : 0);
    f16x8 w0 = bc8((f16)wd.x), w1 = bc8((f16)wd.y), w2 = bc8((f16)wd.z), w3 = bc8((f16)wd.w);
    float s = 0.f;
    f16x8 pe[4];
    #pragma unroll
    for (int g = 0; g < 4; g++) {
      f16x8 v0 = *(const f16x8*)((const char*)sphi + swz(q0, g));
      f16x8 v1 = *(const f16x8*)((const char*)sphi + swz(q1, g));
      f16x8 v2 = *(const f16x8*)((const char*)sphi + swz(q2, g));
      f16x8 v3 = *(const f16x8*)((const char*)sphi + swz(q3, g));
      f16x8 agg = v0*w0 + v1*w1 + v2*w2 + v3*w3;
      #pragma unroll
      for (int j = 0; j < 8; j++) { float e = xexp2((float)agg[j]); s += e; pe[g][j] = (f16)e; }
    }
    f16x8 iv = bc8((f16)xrcp(s));
    size_t opix = ibase + (size_t)gh*WD + gw;
    #pragma unroll
    for (int g = 0; g < 4; g++)
      *(f16x8*)(Aout + (size_t)g*PLANE + opix*8) = pe[g]*iv;
  }
}

// ---------------- fused message-pass pair (iters 3,4 / 5,6); plane-major ----------------
__global__ __launch_bounds__(512, 6) void mp2_kernel(const f16* __restrict__ Ain,
                                                     const float* __restrict__ wb,
                                                     f16* __restrict__ Aout) {
  __shared__ f16 amid[612*32];

  const int blk  = blockIdx.x;          // 1024
  const int xcd  = blk & 7;
  const int q    = blk >> 3;
  const int img  = xcd + ((q >> 5) << 3);
  const int tile = q & 31;
  const int th0  = (tile >> 2) * 16;
  const int tw0  = (tile & 3) * 32;
  const size_t ibase = (size_t)img * HD * WD;

  for (int p = threadIdx.x; p < 612; p += 512) {
    int r = p / 34, cc = p - r*34;
    int gh = th0 - 1 + r, gw = tw0 - 1 + cc;
    bool inimg = ((unsigned)gh < (unsigned)HD) && ((unsigned)gw < (unsigned)WD);
    int ghc = min(max(gh, 0), HD-1), gwc = min(max(gw, 0), WD-1);
    float4 wd = inimg ? ((const float4*)wb)[ibase + gh*WD + gw] : make_float4(0.f,0.f,0.f,0.f);
    int hu = ghc + ((ghc < HD-1) ? 1 : 0);
    int hd = ghc - ((ghc > 0)    ? 1 : 0);
    int wl = gwc + ((gwc < WD-1) ? 1 : 0);
    int wr = gwc - ((gwc > 0)    ? 1 : 0);

    const size_t iu_ = ibase + (size_t)hu*WD + gwc;
    const size_t id_ = ibase + (size_t)hd*WD + gwc;
    const size_t il_ = ibase + (size_t)ghc*WD + wl;
    const size_t ir_ = ibase + (size_t)ghc*WD + wr;
    f16x8 w0 = bc8((f16)wd.x), w1 = bc8((f16)wd.y), w2 = bc8((f16)wd.z), w3 = bc8((f16)wd.w);
    float s = 0.f;
    f16x8 pe[4];
    #pragma unroll
    for (int g = 0; g < 4; g++) {
      const f16* pg = Ain + (size_t)g*PLANE;
      f16x8 v0 = *(const f16x8*)(pg + iu_*8);
      f16x8 v1 = *(const f16x8*)(pg + id_*8);
      f16x8 v2 = *(const f16x8*)(pg + il_*8);
      f16x8 v3 = *(const f16x8*)(pg + ir_*8);
      f16x8 agg = v0*w0 + v1*w1 + v2*w2 + v3*w3;
      #pragma unroll
      for (int j = 0; j < 8; j++) { float e = xexp2((float)agg[j]); s += e; pe[g][j] = (f16)e; }
    }
    f16x8 iv = bc8((f16)xrcp(s));
    #pragma unroll
    for (int g = 0; g < 4; g++)
      *(f16x8*)((char*)amid + swz(p, g)) = pe[g]*iv;
  }
  __syncthreads();

  {
    int r2 = threadIdx.x >> 5, c2 = threadIdx.x & 31;
    int gh = th0 + r2, gw = tw0 + c2;
    int rm = r2 + 1, cm = c2 + 1;
    float4 wd = ((const float4*)wb)[ibase + gh*WD + gw];
    int q0 = (rm + ((gh < HD-1) ? 1 : 0))*34 + cm;
    int q1 = (rm - ((gh > 0)    ? 1 : 0))*34 + cm;
    int q2 = rm*34 + cm + ((gw < WD-1) ? 1 : 0);
    int q3 = rm*34 + cm - ((gw > 0)    ? 1 : 0);
    f16x8 w0 = bc8((f16)wd.x), w1 = bc8((f16)wd.y), w2 = bc8((f16)wd.z), w3 = bc8((f16)wd.w);
    float s = 0.f;
    f16x8 pe[4];
    #pragma unroll
    for (int g = 0; g < 4; g++) {
      f16x8 v0 = *(const f16x8*)((const char*)amid + swz(q0, g));
      f16x8 v1 = *(const f16x8*)((const char*)amid + swz(q1, g));
      f16x8 v2 = *(const f16x8*)((const char*)amid + swz(q2, g));
      f16x8 v3 = *(const f16x8*)((const char*)amid + swz(q3, g));
      f16x8 agg = v0*w0 + v1*w1 + v2*w2 + v3*w3;
      #pragma unroll
      for (int j = 0; j < 8; j++) { float e = xexp2((float)agg[j]); s += e; pe[g][j] = (f16)e; }
    }
    f16x8 iv = bc8((f16)xrcp(s));
    size_t opix = ibase + (size_t)gh*WD + gw;
    #pragma unroll
    for (int g = 0; g < 4; g++)
      *(f16x8*)(Aout + (size_t)g*PLANE + opix*8) = pe[g]*iv;
  }
}

// ---------------- LAST mp2: iters 7,8 + coalesced f32 A write + fused pool partials ----------------
__global__ __launch_bounds__(512, 2) void mp2last_kernel(const f16* __restrict__ Ain,
                                                         const float* __restrict__ wb,
                                                         const int* __restrict__ X,
                                                         float* __restrict__ AoutF,
                                                         float* __restrict__ part) {
  __shared__ f16 amid[612*32];          // phase A/B stencil buffer; reused as planes
  __shared__ float red[16*33*15];       // [g(row)][33-pad k][15]
  __shared__ int sXt[512];

  const int blk  = blockIdx.x;          // 1024
  const int xcd  = blk & 7;
  const int q    = blk >> 3;
  const int img  = xcd + ((q >> 5) << 3);
  const int tile = q & 31;
  const int th0  = (tile >> 2) * 16;
  const int tw0  = (tile & 3) * 32;
  const size_t ibase = (size_t)img * HD * WD;

  {
    int r = threadIdx.x >> 5, c = threadIdx.x & 31;
    sXt[threadIdx.x] = X[ibase + (size_t)(th0 + r)*WD + tw0 + c];
  }

  for (int p = threadIdx.x; p < 612; p += 512) {
    int r = p / 34, cc = p - r*34;
    int gh = th0 - 1 + r, gw = tw0 - 1 + cc;
    bool inimg = ((unsigned)gh < (unsigned)HD) && ((unsigned)gw < (unsigned)WD);
    int ghc = min(max(gh, 0), HD-1), gwc = min(max(gw, 0), WD-1);
    float4 wd = inimg ? ((const float4*)wb)[ibase + gh*WD + gw] : make_float4(0.f,0.f,0.f,0.f);
    int hu = ghc + ((ghc < HD-1) ? 1 : 0);
    int hd = ghc - ((ghc > 0)    ? 1 : 0);
    int wl = gwc + ((gwc < WD-1) ? 1 : 0);
    int wr = gwc - ((gwc > 0)    ? 1 : 0);

    const size_t iu_ = ibase + (size_t)hu*WD + gwc;
    const size_t id_ = ibase + (size_t)hd*WD + gwc;
    const size_t il_ = ibase + (size_t)ghc*WD + wl;
    const size_t ir_ = ibase + (size_t)ghc*WD + wr;
    f16x8 w0 = bc8((f16)wd.x), w1 = bc8((f16)wd.y), w2 = bc8((f16)wd.z), w3 = bc8((f16)wd.w);
    float s = 0.f;
    f16x8 pe[4];
    #pragma unroll
    for (int g = 0; g < 4; g++) {
      const f16* pg = Ain + (size_t)g*PLANE;
      f16x8 v0 = *(const f16x8*)(pg + iu_*8);
      f16x8 v1 = *(const f16x8*)(pg + id_*8);
      f16x8 v2 = *(const f16x8*)(pg + il_*8);
      f16x8 v3 = *(const f16x8*)(pg + ir_*8);
      f16x8 agg = v0*w0 + v1*w1 + v2*w2 + v3*w3;
      #pragma unroll
      for (int j = 0; j < 8; j++) { float e = xexp2((float)agg[j]); s += e; pe[g][j] = (f16)e; }
    }
    f16x8 iv = bc8((f16)xrcp(s));
    #pragma unroll
    for (int g = 0; g < 4; g++)
      *(f16x8*)((char*)amid + swz(p, g)) = pe[g]*iv;
  }
  __syncthreads();

  f16x8 pe[4];
  {
    int r2 = threadIdx.x >> 5, c2 = threadIdx.x & 31;
    int gh = th0 + r2, gw = tw0 + c2;
    int rm = r2 + 1, cm = c2 + 1;
    float4 wd = ((const float4*)wb)[ibase + gh*WD + gw];
    int q0 = (rm + ((gh < HD-1) ? 1 : 0))*34 + cm;
    int q1 = (rm - ((gh > 0)    ? 1 : 0))*34 + cm;
    int q2 = rm*34 + cm + ((gw < WD-1) ? 1 : 0);
    int q3 = rm*34 + cm - ((gw > 0)    ? 1 : 0);
    f16x8 w0 = bc8((f16)wd.x), w1 = bc8((f16)wd.y), w2 = bc8((f16)wd.z), w3 = bc8((f16)wd.w);
    float s = 0.f;
    #pragma unroll
    for (int g = 0; g < 4; g++) {
      f16x8 v0 = *(const f16x8*)((const char*)amid + swz(q0, g));
      f16x8 v1 = *(const f16x8*)((const char*)amid + swz(q1, g));
      f16x8 v2 = *(const f16x8*)((const char*)amid + swz(q2, g));
      f16x8 v3 = *(const f16x8*)((const char*)amid + swz(q3, g));
      f16x8 agg = v0*w0 + v1*w1 + v2*w2 + v3*w3;
      #pragma unroll
      for (int j = 0; j < 8; j++) { float e = xexp2((float)agg[j]); s += e; pe[g][j] = (f16)e; }
    }
    f16x8 iv = bc8((f16)xrcp(s));
    #pragma unroll
    for (int g = 0; g < 4; g++) pe[g] = pe[g]*iv;
  }

  __syncthreads();
  f16* planes = amid;
  #pragma unroll
  for (int g = 0; g < 4; g++)
    *(f16x8*)((char*)planes + (g*513 + threadIdx.x)*16) = pe[g];
  __syncthreads();
  {
    float* obase = AoutF + ((size_t)(img*HD + th0)*WD + tw0)*32;
    #pragma unroll
    for (int rep = 0; rep < 8; rep++) {
      int flat = rep*512 + threadIdx.x;
      int row = flat >> 8;
      int within = flat & 255;
      int pxr = within >> 3;
      int kq = within & 7;
      int g = kq >> 1, half = kq & 1;
      int pxl = row*32 + pxr;
      f16x4 v = *(const f16x4*)((const char*)planes + (g*513 + pxl)*16 + half*8);
      float4 o;
      o.x = (float)v[0]; o.y = (float)v[1]; o.z = (float)v[2]; o.w = (float)v[3];
      *(float4*)(obase + (size_t)row*WD*32 + pxr*32 + kq*4) = o;
    }
  }

  {
    const int k  = threadIdx.x & 31;
    const int gr = threadIdx.x >> 5;
    const int gq = k >> 3, j = k & 7;
    const float hh = ((float)(th0 + gr) + 0.5f) * (1.f/128.f);
    float s0 = 0.f, sw = 0.f, sw2 = 0.f;
    float col[10];
    #pragma unroll
    for (int c = 0; c < 10; c++) col[c] = 0.f;
    #pragma unroll
    for (int i = 0; i < 32; i++) {
      int px = gr*32 + i;
      float a = (float)*(const f16*)((const char*)planes + (gq*513 + px)*16 + j*2);
      float ww = ((float)(tw0 + i) + 0.5f) * (1.f/128.f);
      s0 += a; sw = fmaf(ww, a, sw); sw2 = fmaf(ww*ww, a, sw2);
      int x = sXt[px];
      #pragma unroll
      for (int c = 0; c < 10; c++) col[c] += (x == c) ? a : 0.f;
    }
    float* rd = &red[(gr*33 + k)*15];
    rd[0] = s0; rd[1] = hh*s0; rd[2] = sw; rd[3] = hh*hh*s0; rd[4] = sw2;
    #pragma unroll
    for (int c = 0; c < 10; c++) rd[5+c] = col[c];
  }
  __syncthreads();
  if (threadIdx.x < 480) {
    int k = threadIdx.x / 15, qq = threadIdx.x - k*15;
    float v = 0.f;
    #pragma unroll
    for (int g = 0; g < 16; g++) v += red[(g*33 + k)*15 + qq];
    part[(((size_t)img*32 + tile)*32 + k)*15 + qq] = v;
  }
}

// ---------------- pooled features, stage 2 ----------------
__global__ __launch_bounds__(256) void pool2_kernel(const float* __restrict__ part,
                                                    float* __restrict__ T) {
  const int t = blockIdx.x * 256 + threadIdx.x;
  if (t >= BB*KK) return;
  const int b = t >> 5, k = t & 31;
  float s[15];
  #pragma unroll
  for (int q = 0; q < 15; q++) s[q] = 0.f;
  for (int cy = 0; cy < 32; cy++) {
    const float* p = part + (((size_t)b*32 + cy)*32 + k)*15;
    #pragma unroll
    for (int q = 0; q < 15; q++) s[q] += p[q];
  }
  float mass = s[0] + 1e-6f;
  float inv  = 1.f / mass;
  float h_c = s[1]*inv, w_c = s[2]*inv, h2 = s[3]*inv, w2 = s[4]*inv;
  float h_sd = sqrtf(fmaxf(h2 - h_c*h_c, 0.f) + 1e-6f);
  float w_sd = sqrtf(fmaxf(w2 - w_c*w_c, 0.f) + 1e-6f);
  float* o = T + (size_t)t*17;
  o[0] = mass * (1.f/16384.f);
  o[1] = h_c; o[2] = w_c;
  #pragma unroll
  for (int c = 0; c < 10; c++) o[3+c] = s[5+c]*inv;
  o[13] = h_c - h_sd; o[14] = h_c + h_sd; o[15] = w_c - w_sd; o[16] = w_c + w_sd;
}

extern "C" void kernel_launch(void* const* d_in, const int* in_sizes, int n_in,
                              void* d_out, int out_size, void* d_ws, size_t ws_size,
                              hipStream_t stream) {
  const int*   X  = (const int*)d_in[0];
  const float* w1 = (const float*)d_in[1];
  const float* b1 = (const float*)d_in[2];
  const float* w2 = (const float*)d_in[3];
  const float* b2 = (const float*)d_in[4];
  const float* w3 = (const float*)d_in[5];
  const float* b3 = (const float*)d_in[6];

  float* out   = (float*)d_out;
  float* A_out = out;                           // (B,H,W,K) f32
  float* T_out = out + (size_t)NPIX * KK;       // (B,K,17)

  char*  ws   = (char*)d_ws;
  f16*   bufA = (f16*)ws;                                   // 32 MB planes (ping)
  f16*   bufB = (f16*)(ws + (size_t)32*1024*1024);          // 32 MB planes (pong); phi first
  float* wb   = (float*)(ws + (size_t)64*1024*1024);        // 8 MB (pre-scaled w')
  float* part = (float*)(ws + (size_t)72*1024*1024);        // ~2 MB

  f16* phi = bufB;
  cnn_kernel<<<dim3(WD/32, HD/16, BB), 512, 0, stream>>>(X, w1, b1, w2, b2, w3, b3, phi);

  affmp2_kernel<<<1024, 512, 0, stream>>>(phi, wb, bufA);              // aff + iters 1,2
  mp2_kernel<<<1024, 512, 0, stream>>>(bufA, wb, bufB);                // iters 3,4
  mp2_kernel<<<1024, 512, 0, stream>>>(bufB, wb, bufA);                // iters 5,6
  mp2last_kernel<<<1024, 512, 0, stream>>>(bufA, wb, X, A_out, part);  // iters 7,8 + pool partials

  pool2_kernel<<<(BB*KK + 255)/256, 256, 0, stream>>>(part, T_out);
}